// Round 16
// baseline (212.824 us; speedup 1.0000x reference)
//
#include <hip/hip_runtime.h>

#define NSEQ   16
#define KVH    8
#define NG     4      // query heads per kv head
#define HD     128
#define BS     16
#define MAXB   256
#define PART   256    // tokens per work item (4 waves x 64)
#define NPART  16
#define NITEMS (NSEQ * KVH * NPART)   // 2048 work items
#define NPAIRS (NSEQ * KVH)           // 128 (s,kvh) pairs
#define WPT    64     // tokens per wave
#define PSTRIDE 520   // floats per partition record: o[512], l[4], m, pad
#define REC_BYTES ((size_t)NITEMS * PSTRIDE * 4)
#define SCALE_F 0.08838834764831845f
#define NWORKERS 1024

// agent-scope (device-coherent) float load: bypasses stale L1/L2 lines,
// reads from the coherence point. Used by pair-closers to read records
// written by blocks on other XCDs (Guideline 16).
__device__ __forceinline__ float cohld(const float* p) {
    return __hip_atomic_load(p, __ATOMIC_RELAXED, __HIP_MEMORY_SCOPE_AGENT);
}

// Fused kernel: r15's partial body (block work stealing, 4 independent waves,
// wave-local softmax, contiguous-V PV) + inline per-pair reduce.
// Close protocol: after an item's record is written (+syncthreads drain),
// tid0: __threadfence (release: L2 writeback) + atomicAdd(pair_done[pair]).
// The block seeing old==15 is the closer: __threadfence (acquire) + reduce
// the pair's <=16 records via agent-coherent loads -> write final output.
// Saves kernel2's launch + drain and reads records L2-warm.
__global__ __launch_bounds__(256) void pa_fused_kernel(
    const float* __restrict__ query,
    const float* __restrict__ key,
    const float* __restrict__ value,
    const float* __restrict__ key_cache,
    const float* __restrict__ value_cache,
    const int*   __restrict__ block_tables,
    const int*   __restrict__ context_lens,
    float*       __restrict__ ws,
    unsigned int* __restrict__ counter,    // [0]; pair_done = counter+1 .. +128
    float*       __restrict__ out)
{
    __shared__ float p_lds[4][NG][WPT];   // per-wave probabilities
    __shared__ float o_lds[4][NG * HD];   // per-wave partial outputs
    __shared__ float ml_lds[4][8];        // per-wave m, l[4]
    __shared__ int   item_s;
    __shared__ int   close_s;

    unsigned int* pair_done = counter + 1;

    const int tid  = threadIdx.x;
    const int wv   = tid >> 6;
    const int lane = tid & 63;

    for (;;) {
        if (tid == 0) item_s = (int)atomicAdd(counter, 1u);
        __syncthreads();                  // B1: item_s write visible
        const int item = item_s;
        __syncthreads();                  // B2: all have read; safe to overwrite later
        if (item >= NITEMS) return;

        const int p    = item & (NPART - 1);
        const int kvh  = (item >> 4) & (KVH - 1);
        const int s    = item >> 7;
        const int pair = item >> 4;       // s*KVH + kvh
        const int ctx  = context_lens[s];
        const int t0   = p * PART;
        const bool active = (t0 < ctx);

        if (active) {
            const int tw0  = t0 + wv * WPT;
            const bool wact = (tw0 < ctx);

            const float* q = query + ((size_t)s * KVH + kvh) * (NG * HD);

            float m_w = -1e30f;
            float l_w[NG] = {0.f, 0.f, 0.f, 0.f};

            if (wact) {
                // ---- QK: one token per lane ----
                const int t  = tw0 + lane;                     // < 4096: in-bounds
                const int bt = block_tables[s * MAXB + (t >> 4)];
                const float* kb = key_cache + (size_t)bt * (KVH * HD * BS)
                                            + (size_t)kvh * (HD * BS) + (t & 15) * 8;

                float sc[NG] = {0.f, 0.f, 0.f, 0.f};
                #pragma unroll
                for (int j = 0; j < 16; ++j) {
                    const float4 ka = *(const float4*)(kb + j * 128);
                    const float4 kc = *(const float4*)(kb + j * 128 + 4);
                    #pragma unroll
                    for (int g = 0; g < NG; ++g) {
                        sc[g] += q[g * HD + j * 8 + 0] * ka.x + q[g * HD + j * 8 + 1] * ka.y
                               + q[g * HD + j * 8 + 2] * ka.z + q[g * HD + j * 8 + 3] * ka.w
                               + q[g * HD + j * 8 + 4] * kc.x + q[g * HD + j * 8 + 5] * kc.y
                               + q[g * HD + j * 8 + 6] * kc.z + q[g * HD + j * 8 + 7] * kc.w;
                    }
                }

                // new-token K correction
                if (t == ctx - 1) {
                    const float4* kn4 = (const float4*)(key + ((size_t)s * KVH + kvh) * HD);
                    float ns[NG] = {0.f, 0.f, 0.f, 0.f};
                    #pragma unroll
                    for (int c = 0; c < 32; ++c) {
                        const float4 k4 = kn4[c];
                        #pragma unroll
                        for (int g = 0; g < NG; ++g) {
                            ns[g] += q[g * HD + c * 4 + 0] * k4.x + q[g * HD + c * 4 + 1] * k4.y
                                   + q[g * HD + c * 4 + 2] * k4.z + q[g * HD + c * 4 + 3] * k4.w;
                        }
                    }
                    #pragma unroll
                    for (int g = 0; g < NG; ++g) sc[g] = ns[g];
                }

                float mv;
                if (t < ctx) {
                    #pragma unroll
                    for (int g = 0; g < NG; ++g) sc[g] *= SCALE_F;
                    mv = fmaxf(fmaxf(sc[0], sc[1]), fmaxf(sc[2], sc[3]));
                } else {
                    #pragma unroll
                    for (int g = 0; g < NG; ++g) sc[g] = -1e30f;
                    mv = -1e30f;
                }

                #pragma unroll
                for (int o = 32; o; o >>= 1) mv = fmaxf(mv, __shfl_xor(mv, o));
                m_w = mv;

                float pr[NG];
                #pragma unroll
                for (int g = 0; g < NG; ++g) {
                    pr[g] = __expf(sc[g] - m_w);
                    p_lds[wv][g][lane] = pr[g];
                    l_w[g] = pr[g];
                }
                #pragma unroll
                for (int o = 32; o; o >>= 1) {
                    l_w[0] += __shfl_xor(l_w[0], o);
                    l_w[1] += __shfl_xor(l_w[1], o);
                    l_w[2] += __shfl_xor(l_w[2], o);
                    l_w[3] += __shfl_xor(l_w[3], o);
                }
            }

            if (lane == 0) {
                ml_lds[wv][0] = m_w;
                #pragma unroll
                for (int g = 0; g < NG; ++g) ml_lds[wv][1 + g] = l_w[g];
            }

            // ---- PV: contiguous 1KB V loads (r15) ----
            if (wact) {
                int btv[4];
                #pragma unroll
                for (int b = 0; b < 4; ++b)
                    btv[b] = block_tables[s * MAXB + (tw0 >> 4) + b];

                const int tl = ctx - 1 - tw0;
                const int tq = lane & 3;
                const int dl = lane >> 2;

                float acc[NG][8];
                #pragma unroll
                for (int g = 0; g < NG; ++g)
                    #pragma unroll
                    for (int sub = 0; sub < 8; ++sub) acc[g][sub] = 0.f;

                #pragma unroll
                for (int b = 0; b < 4; ++b) {
                    if (tw0 + b * 16 < ctx) {
                        const float* vb = value_cache + (size_t)btv[b] * (KVH * HD * BS)
                                                      + (size_t)kvh * (HD * BS);
                        float4 p4[NG];
                        #pragma unroll
                        for (int g = 0; g < NG; ++g)
                            p4[g] = *(const float4*)&p_lds[wv][g][b * 16 + tq * 4];
                        #pragma unroll
                        for (int sub = 0; sub < 8; ++sub) {
                            const float4 v4 = *(const float4*)(vb + sub * 256 + lane * 4);
                            #pragma unroll
                            for (int g = 0; g < NG; ++g)
                                acc[g][sub] += p4[g].x * v4.x + p4[g].y * v4.y
                                             + p4[g].z * v4.z + p4[g].w * v4.w;
                        }
                    }
                }

                #pragma unroll
                for (int g = 0; g < NG; ++g)
                    #pragma unroll
                    for (int sub = 0; sub < 8; ++sub) {
                        float a = acc[g][sub];
                        a += __shfl_xor(a, 1);
                        a += __shfl_xor(a, 2);
                        acc[g][sub] = a;
                    }

                if (tl >= 0 && tl < WPT) {
                    const int btn = block_tables[s * MAXB + ((ctx - 1) >> 4)];
                    const float* vbn = value_cache + (size_t)btn * (KVH * HD * BS)
                                                   + (size_t)kvh * (HD * BS) + ((ctx - 1) & 15);
                    const float* vrow = value + ((size_t)s * KVH + kvh) * HD;
                    #pragma unroll
                    for (int sub = 0; sub < 8; ++sub) {
                        const int d = sub * 16 + dl;
                        const float dv = vrow[d] - vbn[d * BS];
                        #pragma unroll
                        for (int g = 0; g < NG; ++g)
                            acc[g][sub] += p_lds[wv][g][tl] * dv;
                    }
                }

                if (tq == 0) {
                    #pragma unroll
                    for (int g = 0; g < NG; ++g)
                        #pragma unroll
                        for (int sub = 0; sub < 8; ++sub)
                            o_lds[wv][g * HD + sub * 16 + dl] = acc[g][sub];
                }
            } else {
                #pragma unroll
                for (int i = 0; i < 8; ++i) o_lds[wv][i * 64 + lane] = 0.f;
            }

            __syncthreads();   // merge the 4 wave records

            const float m0 = ml_lds[0][0], m1 = ml_lds[1][0], m2 = ml_lds[2][0], m3 = ml_lds[3][0];
            const float M  = fmaxf(fmaxf(m0, m1), fmaxf(m2, m3));
            const float w0 = __expf(m0 - M), w1 = __expf(m1 - M);
            const float w2 = __expf(m2 - M), w3 = __expf(m3 - M);

            float* rec = ws + (size_t)item * PSTRIDE;
            #pragma unroll
            for (int r = 0; r < 2; ++r) {
                const int idx = tid + r * 256;
                rec[idx] = w0 * o_lds[0][idx] + w1 * o_lds[1][idx]
                         + w2 * o_lds[2][idx] + w3 * o_lds[3][idx];
            }
            if (tid < NG) {
                rec[512 + tid] = w0 * ml_lds[0][1 + tid] + w1 * ml_lds[1][1 + tid]
                               + w2 * ml_lds[2][1 + tid] + w3 * ml_lds[3][1 + tid];
            }
            if (tid == 4) rec[516] = M;

            __syncthreads();   // B3: drain record stores (vmcnt(0) before barrier)
        }

        // ---- close protocol (uniform for active and inactive items) ----
        if (tid == 0) {
            __threadfence();                               // release: L2 writeback
            const unsigned old = atomicAdd(&pair_done[pair], 1u);
            close_s = (old == NPART - 1) ? 1 : 0;
        }
        __syncthreads();                                   // B4: close_s visible

        if (close_s) {
            __threadfence();                               // acquire side
            // ---- inline reduce of this pair's records ----
            const int np = (ctx + PART - 1) / PART;
            const float* base = ws + (size_t)pair * NPART * PSTRIDE;

            float M = -1e30f;
            for (int p2 = 0; p2 < np; ++p2)
                M = fmaxf(M, cohld(base + p2 * PSTRIDE + 516));

            #pragma unroll
            for (int half = 0; half < 2; ++half) {
                const int g = (tid >> 7) + half * 2;       // 0..3
                const int d = tid & 127;
                float L = 0.f, acc = 0.f;
                for (int p2 = 0; p2 < np; ++p2) {
                    const float* rec = base + p2 * PSTRIDE;
                    const float w = __expf(cohld(rec + 516) - M);
                    L   += w * cohld(rec + 512 + g);
                    acc += w * cohld(rec + g * HD + d);
                }
                out[(size_t)s * (KVH * NG * HD) + (size_t)(kvh * NG + g) * HD + d] = acc / L;
            }
        }
        // next grab's B1 separates this item's LDS reuse
    }
}

extern "C" void kernel_launch(void* const* d_in, const int* in_sizes, int n_in,
                              void* d_out, int out_size, void* d_ws, size_t ws_size,
                              hipStream_t stream) {
    const float* query       = (const float*)d_in[0];
    const float* key         = (const float*)d_in[1];
    const float* value       = (const float*)d_in[2];
    const float* key_cache   = (const float*)d_in[3];
    const float* value_cache = (const float*)d_in[4];
    const int*   block_tables  = (const int*)d_in[5];
    const int*   context_lens  = (const int*)d_in[6];
    // d_in[7] slot_mapping unused: derivable from context_lens + block_tables

    float* out = (float*)d_out;
    float* ws  = (float*)d_ws;   // records 8.52MB/2: 2048*520*4 = 4.26 MB, then counters
    unsigned int* counter = (unsigned int*)((char*)d_ws + REC_BYTES);

    // zero steal-counter [1] + pair_done [128] in one tiny async memset
    (void)hipMemsetAsync(counter, 0, (1 + NPAIRS) * sizeof(unsigned int), stream);
    pa_fused_kernel<<<NWORKERS, 256, 0, stream>>>(
        query, key, value, key_cache, value_cache, block_tables, context_lens,
        ws, counter, out);
}

// Round 17
// 82.707 us; speedup vs baseline: 2.5732x; 2.5732x over previous
//
#include <hip/hip_runtime.h>

#define NSEQ   16
#define KVH    8
#define NG     4      // query heads per kv head
#define HD     128
#define BS     16
#define MAXB   256
#define PART   256    // tokens per work item (4 waves x 64)
#define NPART  16
#define NITEMS (NSEQ * KVH * NPART)   // 2048 work items
#define WPT    64     // tokens per wave
#define PSTRIDE 520   // floats per partition record: o[512], l[4], m, pad
#define REC_BYTES ((size_t)NITEMS * PSTRIDE * 4)
#define SCALE_F 0.08838834764831845f
#define NWORKERS 1024

typedef float vf4 __attribute__((ext_vector_type(4)));
__device__ __forceinline__ float4 ldnt4f(const float* p) {
    vf4 v = __builtin_nontemporal_load((const vf4*)p);
    return make_float4(v[0], v[1], v[2], v[3]);
}

// Kernel 1: r15's structure (block work stealing, two-barrier grab, 4
// independent waves x 64 tokens, wave-local softmax, contiguous-V PV, single
// merge barrier). ONE change: CACHE PARTITIONING. Items with (p&3)==3 (~25%
// of KV demand, ~71MB) use non-temporal KV loads (no L3 allocation); the
// remaining ~214MB allocating stream FITS the 256MB Infinity Cache and stays
// resident across graph replays instead of cyclically thrashing (~50% hits).
// MSHR model: per-CU read BW = outstanding-line slots x 64B / eff-latency;
// raising L3 hit fraction is the only remaining latency lever (r14: all-nt
// = all-HBM = slower; r3-r15: occupancy/balance/depth/contiguity all flat).
__global__ __launch_bounds__(256) void pa_partial_kernel(
    const float* __restrict__ query,
    const float* __restrict__ key,
    const float* __restrict__ value,
    const float* __restrict__ key_cache,
    const float* __restrict__ value_cache,
    const int*   __restrict__ block_tables,
    const int*   __restrict__ context_lens,
    float*       __restrict__ ws,
    unsigned int* __restrict__ counter)
{
    __shared__ float p_lds[4][NG][WPT];   // per-wave probabilities
    __shared__ float o_lds[4][NG * HD];   // per-wave partial outputs
    __shared__ float ml_lds[4][8];        // per-wave m, l[4]
    __shared__ int   item_s;

    const int tid  = threadIdx.x;
    const int wv   = tid >> 6;
    const int lane = tid & 63;

    for (;;) {
        if (tid == 0) item_s = (int)atomicAdd(counter, 1u);
        __syncthreads();                  // B1: item_s write visible
        const int item = item_s;
        __syncthreads();                  // B2: all have read; safe to overwrite later
        if (item >= NITEMS) return;

        const int p   = item & (NPART - 1);
        const int kvh = (item >> 4) & (KVH - 1);
        const int s   = item >> 7;
        const int ctx = context_lens[s];
        const int t0  = p * PART;
        if (t0 >= ctx) continue;          // barrier-safe skip

        const bool ntp = ((p & 3) == 3);  // wave-uniform nt decision (25% of items)

        const int tw0  = t0 + wv * WPT;
        const bool wact = (tw0 < ctx);

        const float* q = query + ((size_t)s * KVH + kvh) * (NG * HD);

        float m_w = -1e30f;
        float l_w[NG] = {0.f, 0.f, 0.f, 0.f};

        if (wact) {
            // ---- QK: one token per lane ----
            const int t  = tw0 + lane;                     // < 4096: in-bounds
            const int bt = block_tables[s * MAXB + (t >> 4)];
            const float* kb = key_cache + (size_t)bt * (KVH * HD * BS)
                                        + (size_t)kvh * (HD * BS) + (t & 15) * 8;

            float sc[NG] = {0.f, 0.f, 0.f, 0.f};
            if (ntp) {
                #pragma unroll
                for (int j = 0; j < 16; ++j) {
                    const float4 ka = ldnt4f(kb + j * 128);
                    const float4 kc = ldnt4f(kb + j * 128 + 4);
                    #pragma unroll
                    for (int g = 0; g < NG; ++g) {
                        sc[g] += q[g * HD + j * 8 + 0] * ka.x + q[g * HD + j * 8 + 1] * ka.y
                               + q[g * HD + j * 8 + 2] * ka.z + q[g * HD + j * 8 + 3] * ka.w
                               + q[g * HD + j * 8 + 4] * kc.x + q[g * HD + j * 8 + 5] * kc.y
                               + q[g * HD + j * 8 + 6] * kc.z + q[g * HD + j * 8 + 7] * kc.w;
                    }
                }
            } else {
                #pragma unroll
                for (int j = 0; j < 16; ++j) {
                    const float4 ka = *(const float4*)(kb + j * 128);
                    const float4 kc = *(const float4*)(kb + j * 128 + 4);
                    #pragma unroll
                    for (int g = 0; g < NG; ++g) {
                        sc[g] += q[g * HD + j * 8 + 0] * ka.x + q[g * HD + j * 8 + 1] * ka.y
                               + q[g * HD + j * 8 + 2] * ka.z + q[g * HD + j * 8 + 3] * ka.w
                               + q[g * HD + j * 8 + 4] * kc.x + q[g * HD + j * 8 + 5] * kc.y
                               + q[g * HD + j * 8 + 6] * kc.z + q[g * HD + j * 8 + 7] * kc.w;
                    }
                }
            }

            // new-token K correction: token ctx-1's key comes from the `key` input
            if (t == ctx - 1) {
                const float4* kn4 = (const float4*)(key + ((size_t)s * KVH + kvh) * HD);
                float ns[NG] = {0.f, 0.f, 0.f, 0.f};
                #pragma unroll
                for (int c = 0; c < 32; ++c) {
                    const float4 k4 = kn4[c];
                    #pragma unroll
                    for (int g = 0; g < NG; ++g) {
                        ns[g] += q[g * HD + c * 4 + 0] * k4.x + q[g * HD + c * 4 + 1] * k4.y
                               + q[g * HD + c * 4 + 2] * k4.z + q[g * HD + c * 4 + 3] * k4.w;
                    }
                }
                #pragma unroll
                for (int g = 0; g < NG; ++g) sc[g] = ns[g];
            }

            float mv;
            if (t < ctx) {
                #pragma unroll
                for (int g = 0; g < NG; ++g) sc[g] *= SCALE_F;
                mv = fmaxf(fmaxf(sc[0], sc[1]), fmaxf(sc[2], sc[3]));
            } else {
                #pragma unroll
                for (int g = 0; g < NG; ++g) sc[g] = -1e30f;
                mv = -1e30f;
            }

            #pragma unroll
            for (int o = 32; o; o >>= 1) mv = fmaxf(mv, __shfl_xor(mv, o));
            m_w = mv;

            float pr[NG];
            #pragma unroll
            for (int g = 0; g < NG; ++g) {
                pr[g] = __expf(sc[g] - m_w);
                p_lds[wv][g][lane] = pr[g];
                l_w[g] = pr[g];
            }
            #pragma unroll
            for (int o = 32; o; o >>= 1) {
                l_w[0] += __shfl_xor(l_w[0], o);
                l_w[1] += __shfl_xor(l_w[1], o);
                l_w[2] += __shfl_xor(l_w[2], o);
                l_w[3] += __shfl_xor(l_w[3], o);
            }
        }

        if (lane == 0) {
            ml_lds[wv][0] = m_w;
            #pragma unroll
            for (int g = 0; g < NG; ++g) ml_lds[wv][1 + g] = l_w[g];
        }

        // ---- PV: contiguous 1KB V loads (r15), nt variant for ntp items ----
        if (wact) {
            int btv[4];
            #pragma unroll
            for (int b = 0; b < 4; ++b)
                btv[b] = block_tables[s * MAXB + (tw0 >> 4) + b];  // uniform, in-bounds

            const int tl = ctx - 1 - tw0;
            const int tq = lane & 3;          // token-quad within block
            const int dl = lane >> 2;         // d sub-index 0..15

            float acc[NG][8];
            #pragma unroll
            for (int g = 0; g < NG; ++g)
                #pragma unroll
                for (int sub = 0; sub < 8; ++sub) acc[g][sub] = 0.f;

            #pragma unroll
            for (int b = 0; b < 4; ++b) {
                if (tw0 + b * 16 < ctx) {     // skip fully-masked blocks
                    const float* vb = value_cache + (size_t)btv[b] * (KVH * HD * BS)
                                                  + (size_t)kvh * (HD * BS);
                    float4 p4[NG];
                    #pragma unroll
                    for (int g = 0; g < NG; ++g)
                        p4[g] = *(const float4*)&p_lds[wv][g][b * 16 + tq * 4];
                    if (ntp) {
                        #pragma unroll
                        for (int sub = 0; sub < 8; ++sub) {
                            const float4 v4 = ldnt4f(vb + sub * 256 + lane * 4);
                            #pragma unroll
                            for (int g = 0; g < NG; ++g)
                                acc[g][sub] += p4[g].x * v4.x + p4[g].y * v4.y
                                             + p4[g].z * v4.z + p4[g].w * v4.w;
                        }
                    } else {
                        #pragma unroll
                        for (int sub = 0; sub < 8; ++sub) {
                            const float4 v4 = *(const float4*)(vb + sub * 256 + lane * 4);
                            #pragma unroll
                            for (int g = 0; g < NG; ++g)
                                acc[g][sub] += p4[g].x * v4.x + p4[g].y * v4.y
                                             + p4[g].z * v4.z + p4[g].w * v4.w;
                        }
                    }
                }
            }

            // reduce the 4 token-quad groups
            #pragma unroll
            for (int g = 0; g < NG; ++g)
                #pragma unroll
                for (int sub = 0; sub < 8; ++sub) {
                    float a = acc[g][sub];
                    a += __shfl_xor(a, 1);
                    a += __shfl_xor(a, 2);
                    acc[g][sub] = a;
                }

            // new-token V correction (post-reduce; all 4 copies stay identical)
            if (tl >= 0 && tl < WPT) {
                const int btn = block_tables[s * MAXB + ((ctx - 1) >> 4)];
                const float* vbn = value_cache + (size_t)btn * (KVH * HD * BS)
                                               + (size_t)kvh * (HD * BS) + ((ctx - 1) & 15);
                const float* vrow = value + ((size_t)s * KVH + kvh) * HD;
                #pragma unroll
                for (int sub = 0; sub < 8; ++sub) {
                    const int d = sub * 16 + dl;
                    const float dv = vrow[d] - vbn[d * BS];
                    #pragma unroll
                    for (int g = 0; g < NG; ++g)
                        acc[g][sub] += p_lds[wv][g][tl] * dv;
                }
            }

            if (tq == 0) {
                #pragma unroll
                for (int g = 0; g < NG; ++g)
                    #pragma unroll
                    for (int sub = 0; sub < 8; ++sub)
                        o_lds[wv][g * HD + sub * 16 + dl] = acc[g][sub];
            }
        } else {
            #pragma unroll
            for (int i = 0; i < 8; ++i) o_lds[wv][i * 64 + lane] = 0.f;
        }

        __syncthreads();   // merge the 4 wave records

        const float m0 = ml_lds[0][0], m1 = ml_lds[1][0], m2 = ml_lds[2][0], m3 = ml_lds[3][0];
        const float M  = fmaxf(fmaxf(m0, m1), fmaxf(m2, m3));
        const float w0 = __expf(m0 - M), w1 = __expf(m1 - M);
        const float w2 = __expf(m2 - M), w3 = __expf(m3 - M);

        float* rec = ws + (size_t)item * PSTRIDE;
        #pragma unroll
        for (int r = 0; r < 2; ++r) {
            const int idx = tid + r * 256;
            rec[idx] = w0 * o_lds[0][idx] + w1 * o_lds[1][idx]
                     + w2 * o_lds[2][idx] + w3 * o_lds[3][idx];
        }
        if (tid < NG) {
            rec[512 + tid] = w0 * ml_lds[0][1 + tid] + w1 * ml_lds[1][1 + tid]
                           + w2 * ml_lds[2][1 + tid] + w3 * ml_lds[3][1 + tid];
        }
        if (tid == 4) rec[516] = M;
        // next grab's B1 separates this item's o_lds reads from the next item's writes
    }
}

// Kernel 2: LSE-combine partitions -> output. One (seq, kvh, g) per block.
__global__ __launch_bounds__(128) void pa_reduce_kernel(
    const float* __restrict__ ws,
    const int*   __restrict__ context_lens,
    float*       __restrict__ out)
{
    const int b    = blockIdx.x;        // ((s*KVH)+kvh)*NG + g
    const int g    = b & 3;
    const int pair = b >> 2;            // s*KVH + kvh
    const int s    = pair >> 3;
    const int kvh  = pair & 7;
    const int ctx  = context_lens[s];
    const int np   = (ctx + PART - 1) / PART;

    const int d = threadIdx.x;
    const float* base = ws + (size_t)pair * NPART * PSTRIDE;

    float M = -1e30f;
    for (int p2 = 0; p2 < np; ++p2) M = fmaxf(M, base[p2 * PSTRIDE + 516]);

    float L = 0.f, acc = 0.f;
    for (int p2 = 0; p2 < np; ++p2) {
        const float* rec = base + p2 * PSTRIDE;
        const float w = __expf(rec[516] - M);
        L   += w * rec[512 + g];
        acc += w * rec[g * HD + d];
    }

    out[(size_t)s * (KVH * NG * HD) + (size_t)(kvh * NG + g) * HD + d] = acc / L;
}

extern "C" void kernel_launch(void* const* d_in, const int* in_sizes, int n_in,
                              void* d_out, int out_size, void* d_ws, size_t ws_size,
                              hipStream_t stream) {
    const float* query       = (const float*)d_in[0];
    const float* key         = (const float*)d_in[1];
    const float* value       = (const float*)d_in[2];
    const float* key_cache   = (const float*)d_in[3];
    const float* value_cache = (const float*)d_in[4];
    const int*   block_tables  = (const int*)d_in[5];
    const int*   context_lens  = (const int*)d_in[6];
    // d_in[7] slot_mapping unused: slot is derivable from context_lens + block_tables

    float* out = (float*)d_out;
    float* ws  = (float*)d_ws;   // records: 2048*520*4 = 4.26 MB, + 4 B counter
    unsigned int* counter = (unsigned int*)((char*)d_ws + REC_BYTES);

    (void)hipMemsetAsync(counter, 0, sizeof(unsigned int), stream);
    pa_partial_kernel<<<NWORKERS, 256, 0, stream>>>(
        query, key, value, key_cache, value_cache, block_tables, context_lens, ws, counter);
    pa_reduce_kernel<<<NSEQ * KVH * NG, 128, 0, stream>>>(ws, context_lens, out);
}